// Round 7
// baseline (52.782 us; speedup 1.0000x reference)
//
#include <hip/hip_runtime.h>

#define BOLTZMAN 0.001987191f
#define ROWS_PER_BLOCK 128  // 8 batches of 16 rows; block spans 32 KB/buffer

__device__ __forceinline__ float rowdot(const float4 a, const float4 b,
                                        const float4 x, const float4 y) {
    return a.x * x.x + a.y * x.y + a.z * x.z + a.w * x.w
         + b.x * y.x + b.y * y.y + b.z * y.z + b.w * y.w;
}

// Single fused kernel, NO __syncthreads. Each wave builds the 128
// coefficients in a wave-private LDS slice (same-wave ds_write->ds_read is
// ordered by the wave's instruction stream + lgkmcnt; wave_barrier pins
// compiler ordering). All 16 stream float4 loads are issued BEFORE the
// coefficient loop (256 B/lane in flight) so the build hides under HBM
// latency; build cost amortized over 128 rows/block.
//
// Coefficients (sign/scale/reversal folded; ring slot 0 is dead and carries
// the newest-sample coefficient):
//   A[t] = -scale*mk[64-t] (t>=1), A[0] = -scale*mk[0]   -> v_list / v
//   B[t] =  h[64-t]        (t>=1), B[0] =  h[0]          -> w_list / w_new
//   mk[lag] = autocorrelation of h, scale = mass[0]*kB*T.
__global__ void __launch_bounds__(256) gle_fused(
    const float* __restrict__ v, const float* __restrict__ w_new,
    const float* __restrict__ v_list, const float* __restrict__ w_list,
    const float* __restrict__ h, const float* __restrict__ mass,
    const int* __restrict__ T, float* __restrict__ out, int nrows)
{
    __shared__ float sh_h[4][64];      // wave-private h copy
    __shared__ float sh_coef[4][128];  // wave-private A[0..63], B[0..63]

    const int tid  = threadIdx.x;
    const int wid  = tid >> 6;         // wave id 0..3
    const int lane = tid & 63;
    const int c    = tid & 15;         // 16 lanes per row
    const int base = blockIdx.x * ROWS_PER_BLOCK;
    const int rr   = base + (tid >> 4);        // batch-0 row for this thread
    const bool fast = (base + ROWS_PER_BLOCK) <= nrows;

    // ---- fast path: issue all 8 batches' stream loads up front ----
    float4 x[8], y[8];
    if (fast) {
        #pragma unroll
        for (int i = 0; i < 8; ++i) {          // static indices -> registers
            x[i] = ((const float4*)(v_list + (size_t)(rr + 16 * i) * 64))[c];
            y[i] = ((const float4*)(w_list + (size_t)(rr + 16 * i) * 64))[c];
        }
    }

    // ---- per-wave coefficient build (overlaps the loads above) ----
    sh_h[wid][lane] = h[lane];
    float scale = mass[0] * BOLTZMAN * (float)T[0];
    __builtin_amdgcn_wave_barrier();
    {
        int lag = (lane == 0) ? 0 : (64 - lane);
        float s = 0.0f;
        // sh_h[wid][k] broadcasts (uniform k); sh_h[wid][k+lag] is stride-1
        // across lanes (2-way max = free).
        for (int k = 0; k + lag < 64; ++k)
            s += sh_h[wid][k] * sh_h[wid][k + lag];
        sh_coef[wid][lane]      = -scale * s;                          // A
        sh_coef[wid][64 + lane] = (lane == 0) ? sh_h[wid][0]
                                              : sh_h[wid][64 - lane];  // B
    }
    __builtin_amdgcn_wave_barrier();
    const float4 a = ((const float4*)sh_coef[wid])[c];
    const float4 b = ((const float4*)(sh_coef[wid] + 64))[c];

    if (fast) {
        if (c == 0) {                          // ring slot 0 is dead
            #pragma unroll
            for (int i = 0; i < 8; ++i) {
                x[i].x = v[rr + 16 * i];
                y[i].x = w_new[rr + 16 * i];
            }
        }
        float s[8];
        #pragma unroll
        for (int i = 0; i < 8; ++i) s[i] = rowdot(a, b, x[i], y[i]);
        #pragma unroll
        for (int m = 1; m <= 8; m <<= 1) {     // 8 independent reduce chains
            #pragma unroll
            for (int i = 0; i < 8; ++i) s[i] += __shfl_xor(s[i], m);
        }
        if (c == 0) {
            #pragma unroll
            for (int i = 0; i < 8; ++i) out[rr + 16 * i] = s[i];
        }
    } else {
        // ---- tail path: per-batch guarded loop ----
        #pragma unroll
        for (int i = 0; i < 8; ++i) {
            int r = rr + 16 * i;
            if (r < nrows) {
                float4 xt = ((const float4*)(v_list + (size_t)r * 64))[c];
                float4 yt = ((const float4*)(w_list + (size_t)r * 64))[c];
                if (c == 0) { xt.x = v[r]; yt.x = w_new[r]; }
                float st = rowdot(a, b, xt, yt);
                #pragma unroll
                for (int m = 1; m <= 8; m <<= 1) st += __shfl_xor(st, m);
                if (c == 0) out[r] = st;
            }
        }
    }
}

extern "C" void kernel_launch(void* const* d_in, const int* in_sizes, int n_in,
                              void* d_out, int out_size, void* d_ws, size_t ws_size,
                              hipStream_t stream) {
    const float* v      = (const float*)d_in[0];   // [N,3] f32
    const int*   T      = (const int*)d_in[1];     // scalar int
    /* d_in[2] = dt (unused) */
    const float* mass   = (const float*)d_in[3];   // [N,3] f32 (use [0])
    const float* h      = (const float*)d_in[4];   // [1,1,64] f32
    const float* v_list = (const float*)d_in[5];   // [3N,1,64] f32
    const float* w_list = (const float*)d_in[6];   // [3N,1,64] f32
    const float* w_new  = (const float*)d_in[7];   // [N,3] f32
    float* out  = (float*)d_out;                   // [N,3] f32

    int nrows = in_sizes[0];                       // 3N = 600000

    int blocks = (nrows + ROWS_PER_BLOCK - 1) / ROWS_PER_BLOCK;  // 4688
    gle_fused<<<blocks, 256, 0, stream>>>(v, w_new, v_list, w_list,
                                          h, mass, T, out, nrows);
}